// Round 1
// baseline (3640.972 us; speedup 1.0000x reference)
//
#include <hip/hip_runtime.h>
#include <math.h>

// ---------------- types ----------------
typedef short bf16x8 __attribute__((ext_vector_type(8)));
typedef float floatx4 __attribute__((ext_vector_type(4)));

__device__ __forceinline__ unsigned short f2bf(float f) {
    unsigned int u = __float_as_uint(f);
    u += 0x7fffu + ((u >> 16) & 1u);   // round-to-nearest-even
    return (unsigned short)(u >> 16);
}

// ---------------- RMSNorm: fp32 in -> fp32 out ----------------
// one block (256 thr) per row of 1024
__global__ __launch_bounds__(256) void rmsnorm_kernel(
        const float* __restrict__ x, const float* __restrict__ w, float* __restrict__ out) {
    __shared__ float sred[4];
    int row = blockIdx.x;
    int t = threadIdx.x;
    float4 v = ((const float4*)(x + (size_t)row * 1024))[t];
    float ss = v.x*v.x + v.y*v.y + v.z*v.z + v.w*v.w;
#pragma unroll
    for (int m = 32; m >= 1; m >>= 1) ss += __shfl_xor(ss, m, 64);
    if ((t & 63) == 0) sred[t >> 6] = ss;
    __syncthreads();
    float tot = sred[0] + sred[1] + sred[2] + sred[3];
    float r = rsqrtf(tot * (1.0f / 1024.0f) + 1e-6f);
    float4 wv = ((const float4*)w)[t];
    float4 o;
    o.x = v.x * r * wv.x; o.y = v.y * r * wv.y; o.z = v.z * r * wv.z; o.w = v.w * r * wv.w;
    ((float4*)(out + (size_t)row * 1024))[t] = o;
}

// ---------------- GEMM: C[M,Nc] = A[M,Kd] * W[Nc,Kd]^T (+res), bf16 MFMA ----------------
// 128x128 tile, BK=32, 256 threads = 4 waves (2x2 of 64x64)
__global__ __launch_bounds__(256) void gemm_kernel(
        const float* __restrict__ A, const float* __restrict__ W,
        const float* __restrict__ res, float* __restrict__ C,
        int Ncols, int Kd) {
    __shared__ __align__(16) unsigned short As[128 * 32];
    __shared__ __align__(16) unsigned short Bs[128 * 32];
    int t = threadIdx.x;
    int bn = blockIdx.x, bm = blockIdx.y;
    int wave = t >> 6, lane = t & 63;
    int wm = wave >> 1, wn = wave & 1;
    int lrow = lane & 15, quad = lane >> 4;
    const int bmBase = bm * 128, bnBase = bn * 128;

    floatx4 acc[4][4] = {};

    for (int k0 = 0; k0 < Kd; k0 += 32) {
#pragma unroll
        for (int i = 0; i < 4; i++) {
            int idx = t + i * 256;            // 1024 float4 units per tile
            int r = idx >> 3;                 // 8 float4 per 32-wide row
            int c = (idx & 7) << 2;
            float4 av = *(const float4*)(A + (size_t)(bmBase + r) * Kd + k0 + c);
            ushort4 ap;
            ap.x = f2bf(av.x); ap.y = f2bf(av.y); ap.z = f2bf(av.z); ap.w = f2bf(av.w);
            *(ushort4*)&As[r * 32 + c] = ap;
            float4 bv = *(const float4*)(W + (size_t)(bnBase + r) * Kd + k0 + c);
            ushort4 bp;
            bp.x = f2bf(bv.x); bp.y = f2bf(bv.y); bp.z = f2bf(bv.z); bp.w = f2bf(bv.w);
            *(ushort4*)&Bs[r * 32 + c] = bp;
        }
        __syncthreads();
        bf16x8 af[4], bfr[4];
#pragma unroll
        for (int im = 0; im < 4; im++)
            af[im] = *(const bf16x8*)&As[(wm * 64 + im * 16 + lrow) * 32 + quad * 8];
#pragma unroll
        for (int in = 0; in < 4; in++)
            bfr[in] = *(const bf16x8*)&Bs[(wn * 64 + in * 16 + lrow) * 32 + quad * 8];
#pragma unroll
        for (int im = 0; im < 4; im++)
#pragma unroll
            for (int in = 0; in < 4; in++)
                acc[im][in] = __builtin_amdgcn_mfma_f32_16x16x32_bf16(af[im], bfr[in], acc[im][in], 0, 0, 0);
        __syncthreads();
    }

#pragma unroll
    for (int im = 0; im < 4; im++) {
        int gr0 = bmBase + wm * 64 + im * 16 + quad * 4;
#pragma unroll
        for (int in = 0; in < 4; in++) {
            int gc = bnBase + wn * 64 + in * 16 + lrow;
#pragma unroll
            for (int r2 = 0; r2 < 4; r2++) {
                size_t off = (size_t)(gr0 + r2) * Ncols + gc;
                float v = acc[im][in][r2];
                if (res) v += res[off];
                C[off] = v;
            }
        }
    }
}

// ---------------- RoPE + split qkv -> q, k, vT ----------------
// grid: 2048 blocks (n), 512 threads: h = t>>5 (16), j = t&31 (pair j, j+32)
__global__ __launch_bounds__(512) void rope_kernel(
        const float* __restrict__ qkv, float* __restrict__ q,
        float* __restrict__ k, float* __restrict__ vt) {
    int n = blockIdx.x;
    int t = threadIdx.x;
    int h = t >> 5, j = t & 31;
    float inv = powf(10000.0f, -(float)j * (1.0f / 32.0f));
    float ang = (float)n * inv;
    float s, c;
    __sincosf(ang, &s, &c);
    // use accurate versions
    s = sinf(ang); c = cosf(ang);
    const float* base = qkv + (size_t)n * 3072;
    int o1 = h * 64 + j, o2 = o1 + 32;
    float q1 = base[o1],        q2 = base[o2];
    float k1 = base[1024 + o1], k2 = base[1024 + o2];
    float v1 = base[2048 + o1], v2 = base[2048 + o2];
    q[(size_t)n * 1024 + o1] = q1 * c - q2 * s;
    q[(size_t)n * 1024 + o2] = q2 * c + q1 * s;
    k[(size_t)n * 1024 + o1] = k1 * c - k2 * s;
    k[(size_t)n * 1024 + o2] = k2 * c + k1 * s;
    vt[(size_t)o1 * 2048 + n] = v1;
    vt[(size_t)o2 * 2048 + n] = v2;
}

// ---------------- Flash attention (causal), bf16 MFMA ----------------
// grid (32 qblocks, 16 heads), 256 threads = 4 waves; wave w owns q rows w*16..+15
__global__ __launch_bounds__(256) void attn_kernel(
        const float* __restrict__ q, const float* __restrict__ kbuf,
        const float* __restrict__ vt, float* __restrict__ attn) {
    __shared__ __align__(16) unsigned short Qs[64 * 64];
    __shared__ __align__(16) unsigned short Ks[64 * 64];
    __shared__ __align__(16) unsigned short Vs[64 * 64];   // [dim][key]
    __shared__ __align__(16) unsigned short Ps[4 * 16 * 64];
    int qb = blockIdx.x;
    int h  = blockIdx.y;
    int t = threadIdx.x;
    int wave = t >> 6, lane = t & 63;
    int lrow = lane & 15, quad = lane >> 4;

    // stage Q (64 rows x 64 dims)
#pragma unroll
    for (int i = 0; i < 4; i++) {
        int idx = t + i * 256;           // 1024 float4 units, 16 per row
        int r = idx >> 4, c = (idx & 15) << 2;
        float4 v = *(const float4*)(q + (size_t)(qb * 64 + r) * 1024 + h * 64 + c);
        ushort4 p; p.x = f2bf(v.x); p.y = f2bf(v.y); p.z = f2bf(v.z); p.w = f2bf(v.w);
        *(ushort4*)&Qs[r * 64 + c] = p;
    }

    floatx4 oacc[4] = {};
    float mrow[4], lsum[4];
#pragma unroll
    for (int r2 = 0; r2 < 4; r2++) { mrow[r2] = -INFINITY; lsum[r2] = 0.0f; }

    for (int kt = 0; kt <= qb; ++kt) {
        __syncthreads();  // previous iter's LDS reads done (also covers Q staging on iter 0)
#pragma unroll
        for (int i = 0; i < 4; i++) {
            int idx = t + i * 256;
            int r = idx >> 4, c = (idx & 15) << 2;
            float4 kv = *(const float4*)(kbuf + (size_t)(kt * 64 + r) * 1024 + h * 64 + c);
            ushort4 kp; kp.x = f2bf(kv.x); kp.y = f2bf(kv.y); kp.z = f2bf(kv.z); kp.w = f2bf(kv.w);
            *(ushort4*)&Ks[r * 64 + c] = kp;
            float4 vv = *(const float4*)(vt + (size_t)(h * 64 + r) * 2048 + kt * 64 + c);
            ushort4 vp; vp.x = f2bf(vv.x); vp.y = f2bf(vv.y); vp.z = f2bf(vv.z); vp.w = f2bf(vv.w);
            *(ushort4*)&Vs[r * 64 + c] = vp;   // r = dim, c = key
        }
        __syncthreads();

        // S = Q K^T  (wave's 16 q rows x 64 keys)
        floatx4 sacc[4] = {};
#pragma unroll
        for (int kk = 0; kk < 64; kk += 32) {
            bf16x8 aq = *(const bf16x8*)&Qs[(wave * 16 + lrow) * 64 + kk + quad * 8];
#pragma unroll
            for (int jn = 0; jn < 4; jn++) {
                bf16x8 bk = *(const bf16x8*)&Ks[(jn * 16 + lrow) * 64 + kk + quad * 8];
                sacc[jn] = __builtin_amdgcn_mfma_f32_16x16x32_bf16(aq, bk, sacc[jn], 0, 0, 0);
            }
        }

        // online softmax per q-row (row = quad*4 + r2, cols across 16-lane group)
#pragma unroll
        for (int r2 = 0; r2 < 4; r2++) {
            int qg = qb * 64 + wave * 16 + quad * 4 + r2;
            float sv[4];
            float rm = -INFINITY;
#pragma unroll
            for (int jn = 0; jn < 4; jn++) {
                float xv = sacc[jn][r2] * 0.125f;
                int kg = kt * 64 + jn * 16 + lrow;
                if (kg > qg) xv = -INFINITY;
                sv[jn] = xv;
                rm = fmaxf(rm, xv);
            }
#pragma unroll
            for (int m = 8; m >= 1; m >>= 1) rm = fmaxf(rm, __shfl_xor(rm, m, 64));
            float mnew = fmaxf(mrow[r2], rm);
            float alpha = expf(mrow[r2] - mnew);
            float rs = 0.0f;
#pragma unroll
            for (int jn = 0; jn < 4; jn++) {
                float p = expf(sv[jn] - mnew);
                rs += p;
                Ps[wave * 1024 + (quad * 4 + r2) * 64 + jn * 16 + lrow] = f2bf(p);
            }
#pragma unroll
            for (int m = 8; m >= 1; m >>= 1) rs += __shfl_xor(rs, m, 64);
            lsum[r2] = lsum[r2] * alpha + rs;
            mrow[r2] = mnew;
#pragma unroll
            for (int jd = 0; jd < 4; jd++) oacc[jd][r2] *= alpha;
        }
        __syncthreads();  // Ps visible

        // O += P V   (P: A-layout from LDS; V: [dim][key] -> contiguous B-frag)
#pragma unroll
        for (int kk = 0; kk < 64; kk += 32) {
            bf16x8 ap = *(const bf16x8*)&Ps[wave * 1024 + lrow * 64 + kk + quad * 8];
#pragma unroll
            for (int jd = 0; jd < 4; jd++) {
                bf16x8 bv = *(const bf16x8*)&Vs[(jd * 16 + lrow) * 64 + kk + quad * 8];
                oacc[jd] = __builtin_amdgcn_mfma_f32_16x16x32_bf16(ap, bv, oacc[jd], 0, 0, 0);
            }
        }
    }

#pragma unroll
    for (int r2 = 0; r2 < 4; r2++) {
        int qg = qb * 64 + wave * 16 + quad * 4 + r2;
        float invl = 1.0f / lsum[r2];
#pragma unroll
        for (int jd = 0; jd < 4; jd++)
            attn[(size_t)qg * 1024 + h * 64 + jd * 16 + lrow] = oacc[jd][r2] * invl;
    }
}

// ---------------- SiLU gate: a[2048,8192] -> g[2048,4096] ----------------
__global__ __launch_bounds__(256) void silu_kernel(
        const float* __restrict__ a, float* __restrict__ g) {
    int i = blockIdx.x * 256 + threadIdx.x;   // float4 units over 2048*1024
    int n = i >> 10, c = (i & 1023) << 2;
    float4 a1 = *(const float4*)(a + (size_t)n * 8192 + c);
    float4 a2 = *(const float4*)(a + (size_t)n * 8192 + 4096 + c);
    float4 o;
    o.x = a1.x / (1.0f + expf(-a1.x)) * a2.x;
    o.y = a1.y / (1.0f + expf(-a1.y)) * a2.y;
    o.z = a1.z / (1.0f + expf(-a1.z)) * a2.z;
    o.w = a1.w / (1.0f + expf(-a1.w)) * a2.w;
    *(float4*)(g + (size_t)n * 4096 + c) = o;
}

// ---------------- launch ----------------
extern "C" void kernel_launch(void* const* d_in, const int* in_sizes, int n_in,
                              void* d_out, int out_size, void* d_ws, size_t ws_size,
                              hipStream_t stream) {
    const float* x     = (const float*)d_in[0];
    const float* qkv_w = (const float*)d_in[1];
    const float* out_w = (const float*)d_in[2];
    const float* w1    = (const float*)d_in[3];
    const float* w2    = (const float*)d_in[4];
    const float* n1    = (const float*)d_in[5];
    const float* n2    = (const float*)d_in[6];

    float* ws = (float*)d_ws;
    float* xbuf  = ws;                       // 2048*1024
    float* hbuf  = xbuf + 2097152;           // 2048*1024
    float* arena = hbuf + 2097152;           // 16,777,216 floats (64 MB)
    float* qkvb  = arena;                    // 2048*3072
    float* qb_   = arena + 6291456;          // 2048*1024
    float* kb_   = qb_ + 2097152;            // 2048*1024
    float* vtb   = kb_ + 2097152;            // 16*64*2048
    float* attnb = vtb + 2097152;            // 2048*1024
    float* abuf  = arena;                    // 2048*8192 (reuses arena; qkv/q/k/vt/attn dead by then)
    float* gbuf  = arena + 16777216;         // 2048*4096

    hipMemcpyAsync(xbuf, x, (size_t)2048 * 1024 * 4, hipMemcpyDeviceToDevice, stream);

    for (int i = 0; i < 6; i++) {
        rmsnorm_kernel<<<2048, 256, 0, stream>>>(xbuf, n1 + (size_t)i * 1024, hbuf);
        gemm_kernel<<<dim3(24, 16), 256, 0, stream>>>(hbuf, qkv_w + (size_t)i * 3072 * 1024,
                                                      nullptr, qkvb, 3072, 1024);
        rope_kernel<<<2048, 512, 0, stream>>>(qkvb, qb_, kb_, vtb);
        attn_kernel<<<dim3(32, 16), 256, 0, stream>>>(qb_, kb_, vtb, attnb);
        gemm_kernel<<<dim3(8, 16), 256, 0, stream>>>(attnb, out_w + (size_t)i * 1024 * 1024,
                                                     xbuf, xbuf, 1024, 1024);
        rmsnorm_kernel<<<2048, 256, 0, stream>>>(xbuf, n2 + (size_t)i * 1024, hbuf);
        gemm_kernel<<<dim3(64, 16), 256, 0, stream>>>(hbuf, w1 + (size_t)i * 8192 * 1024,
                                                      nullptr, abuf, 8192, 1024);
        silu_kernel<<<8192, 256, 0, stream>>>(abuf, gbuf);
        gemm_kernel<<<dim3(8, 16), 256, 0, stream>>>(gbuf, w2 + (size_t)i * 1024 * 4096,
                                                     xbuf, xbuf, 1024, 4096);
    }

    hipMemcpyAsync(d_out, xbuf, (size_t)2048 * 1024 * 4, hipMemcpyDeviceToDevice, stream);
}

// Round 2
// 2108.169 us; speedup vs baseline: 1.7271x; 1.7271x over previous
//
#include <hip/hip_runtime.h>
#include <math.h>

typedef short bf16x8 __attribute__((ext_vector_type(8)));
typedef float floatx4 __attribute__((ext_vector_type(4)));

__device__ __forceinline__ unsigned short f2bf(float f) {
    unsigned int u = __float_as_uint(f);
    u += 0x7fffu + ((u >> 16) & 1u);   // round-to-nearest-even
    return (unsigned short)(u >> 16);
}
__device__ __forceinline__ float bf2f(unsigned short u) {
    return __uint_as_float(((unsigned int)u) << 16);
}
// async global->LDS, 16B per lane; LDS dest = wave-uniform base + lane*16
__device__ __forceinline__ void async16(void* lds, const void* g) {
    __builtin_amdgcn_global_load_lds((const __attribute__((address_space(1))) unsigned int*)g,
                                     (__attribute__((address_space(3))) unsigned int*)lds,
                                     16, 0, 0);
}

// ---------------- weight convert: fp32 -> bf16, one layer's 4 tensors ----------------
// float4-unit segments: qkv 786432 | out 262144 | w1 2097152 | w2 1048576  (total 4194304)
__global__ __launch_bounds__(256) void conv_w(
        const float* __restrict__ qkv, const float* __restrict__ ow,
        const float* __restrict__ w1, const float* __restrict__ w2,
        unsigned short* __restrict__ dst) {
    size_t i = (size_t)blockIdx.x * 256 + threadIdx.x;
    const float* s; size_t off; unsigned short* d;
    if (i < 786432)       { s = qkv; off = i;           d = dst; }
    else if (i < 1048576) { s = ow;  off = i - 786432;  d = dst + 3145728; }
    else if (i < 3145728) { s = w1;  off = i - 1048576; d = dst + 4194304; }
    else                  { s = w2;  off = i - 3145728; d = dst + 12582912; }
    float4 v = ((const float4*)s)[off];
    ushort4 o;
    o.x = f2bf(v.x); o.y = f2bf(v.y); o.z = f2bf(v.z); o.w = f2bf(v.w);
    ((ushort4*)d)[off] = o;
}

// ---------------- RMSNorm: fp32 in -> bf16 out ----------------
__global__ __launch_bounds__(256) void rmsnorm_bf(
        const float* __restrict__ x, const float* __restrict__ w,
        unsigned short* __restrict__ out) {
    __shared__ float sred[4];
    int row = blockIdx.x;
    int t = threadIdx.x;
    float4 v = ((const float4*)(x + (size_t)row * 1024))[t];
    float ss = v.x*v.x + v.y*v.y + v.z*v.z + v.w*v.w;
#pragma unroll
    for (int m = 32; m >= 1; m >>= 1) ss += __shfl_xor(ss, m, 64);
    if ((t & 63) == 0) sred[t >> 6] = ss;
    __syncthreads();
    float tot = sred[0] + sred[1] + sred[2] + sred[3];
    float r = rsqrtf(tot * (1.0f / 1024.0f) + 1e-6f);
    float4 wv = ((const float4*)w)[t];
    ushort4 o;
    o.x = f2bf(v.x * r * wv.x); o.y = f2bf(v.y * r * wv.y);
    o.z = f2bf(v.z * r * wv.z); o.w = f2bf(v.w * r * wv.w);
    ((ushort4*)(out + (size_t)row * 1024))[t] = o;
}

// ---------------- GEMM: C[M,Nc] = A[M,Kd] * W[Nc,Kd]^T, bf16 in ----------------
// 128x128 tile, BK=32, 256 thr = 4 waves (2x2 of 64x64), m97 structure.
// OUTMODE 0: store bf16. OUTMODE 1: fp32 atomicAdd (split-K over blockIdx.z; residual free).
template<int OUTMODE>
__global__ __launch_bounds__(256) void gemm_bf(
        const unsigned short* __restrict__ A, const unsigned short* __restrict__ W,
        void* __restrict__ Cout, int Ncols, int Kd) {
    __shared__ __align__(16) unsigned short As[128 * 32];
    __shared__ __align__(16) unsigned short Bs[128 * 32];
    int t = threadIdx.x;
    int wave = t >> 6, lane = t & 63;
    int wm = wave >> 1, wn = wave & 1;
    int lrow = lane & 15, quad = lane >> 4;
    int bmBase = blockIdx.y * 128, bnBase = blockIdx.x * 128;
    int kslice = Kd / gridDim.z;
    int kBeg = blockIdx.z * kslice, kEnd = kBeg + kslice;

    int sub = lane >> 2;           // row within chunk (16 rows of 64B)
    int colb = (lane & 3) * 8;     // elem col within 32
    int c0 = wave, c1 = wave + 4;  // this wave's chunks (of 8 per tile)

    floatx4 acc[4][4] = {};

    for (int k0 = kBeg; k0 < kEnd; k0 += 32) {
        async16(&As[c0 * 512 + lane * 8], A + (size_t)(bmBase + c0 * 16 + sub) * Kd + k0 + colb);
        async16(&As[c1 * 512 + lane * 8], A + (size_t)(bmBase + c1 * 16 + sub) * Kd + k0 + colb);
        async16(&Bs[c0 * 512 + lane * 8], W + (size_t)(bnBase + c0 * 16 + sub) * Kd + k0 + colb);
        async16(&Bs[c1 * 512 + lane * 8], W + (size_t)(bnBase + c1 * 16 + sub) * Kd + k0 + colb);
        __syncthreads();
        bf16x8 af[4], bfr[4];
#pragma unroll
        for (int im = 0; im < 4; im++)
            af[im] = *(const bf16x8*)&As[(wm * 64 + im * 16 + lrow) * 32 + quad * 8];
#pragma unroll
        for (int in = 0; in < 4; in++)
            bfr[in] = *(const bf16x8*)&Bs[(wn * 64 + in * 16 + lrow) * 32 + quad * 8];
#pragma unroll
        for (int im = 0; im < 4; im++)
#pragma unroll
            for (int in = 0; in < 4; in++)
                acc[im][in] = __builtin_amdgcn_mfma_f32_16x16x32_bf16(af[im], bfr[in], acc[im][in], 0, 0, 0);
        __syncthreads();
    }

#pragma unroll
    for (int im = 0; im < 4; im++) {
        int gr0 = bmBase + wm * 64 + im * 16 + quad * 4;
#pragma unroll
        for (int in = 0; in < 4; in++) {
            int gc = bnBase + wn * 64 + in * 16 + lrow;
#pragma unroll
            for (int r2 = 0; r2 < 4; r2++) {
                size_t off = (size_t)(gr0 + r2) * Ncols + gc;
                if (OUTMODE == 0) ((unsigned short*)Cout)[off] = f2bf(acc[im][in][r2]);
                else              atomicAdd((float*)Cout + off, acc[im][in][r2]);
            }
        }
    }
}

// ---------------- RoPE + split qkv (bf16) -> q, k, vT (bf16) ----------------
__global__ __launch_bounds__(512) void rope_bf(
        const unsigned short* __restrict__ qkv, unsigned short* __restrict__ q,
        unsigned short* __restrict__ k, unsigned short* __restrict__ vt) {
    int n = blockIdx.x;
    int t = threadIdx.x;
    int h = t >> 5, j = t & 31;
    float inv = powf(10000.0f, -(float)j * (1.0f / 32.0f));
    float ang = (float)n * inv;
    float s = sinf(ang), c = cosf(ang);
    const unsigned short* base = qkv + (size_t)n * 3072;
    int o1 = h * 64 + j, o2 = o1 + 32;
    float q1 = bf2f(base[o1]),        q2 = bf2f(base[o2]);
    float k1 = bf2f(base[1024 + o1]), k2 = bf2f(base[1024 + o2]);
    q[(size_t)n * 1024 + o1] = f2bf(q1 * c - q2 * s);
    q[(size_t)n * 1024 + o2] = f2bf(q2 * c + q1 * s);
    k[(size_t)n * 1024 + o1] = f2bf(k1 * c - k2 * s);
    k[(size_t)n * 1024 + o2] = f2bf(k2 * c + k1 * s);
    vt[(size_t)o1 * 2048 + n] = base[2048 + o1];
    vt[(size_t)o2 * 2048 + n] = base[2048 + o2];
}

// ---------------- Flash attention (causal), bf16 in, bf16 out ----------------
// grid (32 qblocks, 16 heads), 256 thr = 4 waves; wave w owns q rows w*16..+15
__global__ __launch_bounds__(256) void attn_bf(
        const unsigned short* __restrict__ q, const unsigned short* __restrict__ kbuf,
        const unsigned short* __restrict__ vt, unsigned short* __restrict__ attn) {
    __shared__ __align__(16) unsigned short Qs[64 * 64];
    __shared__ __align__(16) unsigned short Ks[64 * 64];
    __shared__ __align__(16) unsigned short Vs[64 * 64];   // [dim][key]
    __shared__ __align__(16) unsigned short Ps[4 * 16 * 64];
    int qb = blockIdx.x;
    int h  = blockIdx.y;
    int t = threadIdx.x;
    int wave = t >> 6, lane = t & 63;
    int lrow = lane & 15, quad = lane >> 4;
    int sub8 = lane >> 3;           // row within 8-row chunk
    int col8 = (lane & 7) * 8;      // elem col within 64
    int c0 = wave, c1 = wave + 4;

    // stage Q (64 rows x 64 dims): 8 chunks of 1KB
    async16(&Qs[c0 * 512 + lane * 8], q + (size_t)(qb * 64 + c0 * 8 + sub8) * 1024 + h * 64 + col8);
    async16(&Qs[c1 * 512 + lane * 8], q + (size_t)(qb * 64 + c1 * 8 + sub8) * 1024 + h * 64 + col8);

    floatx4 oacc[4] = {};
    float mrow[4], lsum[4];
#pragma unroll
    for (int r2 = 0; r2 < 4; r2++) { mrow[r2] = -INFINITY; lsum[r2] = 0.0f; }

    for (int kt = 0; kt <= qb; ++kt) {
        __syncthreads();  // prior iter's LDS reads done (also drains Q asyncs on iter 0)
        async16(&Ks[c0 * 512 + lane * 8], kbuf + (size_t)(kt * 64 + c0 * 8 + sub8) * 1024 + h * 64 + col8);
        async16(&Ks[c1 * 512 + lane * 8], kbuf + (size_t)(kt * 64 + c1 * 8 + sub8) * 1024 + h * 64 + col8);
        async16(&Vs[c0 * 512 + lane * 8], vt + (size_t)(h * 64 + c0 * 8 + sub8) * 2048 + kt * 64 + col8);
        async16(&Vs[c1 * 512 + lane * 8], vt + (size_t)(h * 64 + c1 * 8 + sub8) * 2048 + kt * 64 + col8);
        __syncthreads();

        // S = Q K^T (wave's 16 q rows x 64 keys)
        floatx4 sacc[4] = {};
#pragma unroll
        for (int kk = 0; kk < 64; kk += 32) {
            bf16x8 aq = *(const bf16x8*)&Qs[(wave * 16 + lrow) * 64 + kk + quad * 8];
#pragma unroll
            for (int jn = 0; jn < 4; jn++) {
                bf16x8 bk = *(const bf16x8*)&Ks[(jn * 16 + lrow) * 64 + kk + quad * 8];
                sacc[jn] = __builtin_amdgcn_mfma_f32_16x16x32_bf16(aq, bk, sacc[jn], 0, 0, 0);
            }
        }

        // online softmax per q-row (row = quad*4 + r2, 16 cols per 16-lane group)
#pragma unroll
        for (int r2 = 0; r2 < 4; r2++) {
            int qg = qb * 64 + wave * 16 + quad * 4 + r2;
            float sv[4];
            float rm = -INFINITY;
#pragma unroll
            for (int jn = 0; jn < 4; jn++) {
                float xv = sacc[jn][r2] * 0.125f;
                int kg = kt * 64 + jn * 16 + lrow;
                if (kg > qg) xv = -INFINITY;
                sv[jn] = xv;
                rm = fmaxf(rm, xv);
            }
#pragma unroll
            for (int m = 8; m >= 1; m >>= 1) rm = fmaxf(rm, __shfl_xor(rm, m, 64));
            float mnew = fmaxf(mrow[r2], rm);
            float alpha = __expf(mrow[r2] - mnew);
            float rs = 0.0f;
#pragma unroll
            for (int jn = 0; jn < 4; jn++) {
                float p = __expf(sv[jn] - mnew);
                rs += p;
                Ps[wave * 1024 + (quad * 4 + r2) * 64 + jn * 16 + lrow] = f2bf(p);
            }
#pragma unroll
            for (int m = 8; m >= 1; m >>= 1) rs += __shfl_xor(rs, m, 64);
            lsum[r2] = lsum[r2] * alpha + rs;
            mrow[r2] = mnew;
#pragma unroll
            for (int jd = 0; jd < 4; jd++) oacc[jd][r2] *= alpha;
        }
        __syncthreads();  // Ps visible

        // O += P V
#pragma unroll
        for (int kk = 0; kk < 64; kk += 32) {
            bf16x8 ap = *(const bf16x8*)&Ps[wave * 1024 + lrow * 64 + kk + quad * 8];
#pragma unroll
            for (int jd = 0; jd < 4; jd++) {
                bf16x8 bv = *(const bf16x8*)&Vs[(jd * 16 + lrow) * 64 + kk + quad * 8];
                oacc[jd] = __builtin_amdgcn_mfma_f32_16x16x32_bf16(ap, bv, oacc[jd], 0, 0, 0);
            }
        }
    }

#pragma unroll
    for (int r2 = 0; r2 < 4; r2++) {
        int qg = qb * 64 + wave * 16 + quad * 4 + r2;
        float invl = 1.0f / lsum[r2];
#pragma unroll
        for (int jd = 0; jd < 4; jd++)
            attn[(size_t)qg * 1024 + h * 64 + jd * 16 + lrow] = f2bf(oacc[jd][r2] * invl);
    }
}

// ---------------- SiLU gate: a[2048,8192] bf16 -> g[2048,4096] bf16 ----------------
__global__ __launch_bounds__(256) void silu_bf(
        const unsigned short* __restrict__ a, unsigned short* __restrict__ g) {
    int i = blockIdx.x * 256 + threadIdx.x;   // ushort4 unit over 2048*4096
    int n = i >> 10, c = (i & 1023) << 2;
    ushort4 a1 = *(const ushort4*)(a + (size_t)n * 8192 + c);
    ushort4 a2 = *(const ushort4*)(a + (size_t)n * 8192 + 4096 + c);
    float x0 = bf2f(a1.x), x1 = bf2f(a1.y), x2 = bf2f(a1.z), x3 = bf2f(a1.w);
    ushort4 o;
    o.x = f2bf(x0 / (1.0f + __expf(-x0)) * bf2f(a2.x));
    o.y = f2bf(x1 / (1.0f + __expf(-x1)) * bf2f(a2.y));
    o.z = f2bf(x2 / (1.0f + __expf(-x2)) * bf2f(a2.z));
    o.w = f2bf(x3 / (1.0f + __expf(-x3)) * bf2f(a2.w));
    *(ushort4*)(g + (size_t)n * 4096 + c) = o;
}

// ---------------- launch ----------------
extern "C" void kernel_launch(void* const* d_in, const int* in_sizes, int n_in,
                              void* d_out, int out_size, void* d_ws, size_t ws_size,
                              hipStream_t stream) {
    const float* x     = (const float*)d_in[0];
    const float* qkv_w = (const float*)d_in[1];
    const float* out_w = (const float*)d_in[2];
    const float* w1    = (const float*)d_in[3];
    const float* w2    = (const float*)d_in[4];
    const float* n1    = (const float*)d_in[5];
    const float* n2    = (const float*)d_in[6];

    char* ws = (char*)d_ws;
    float*          xbuf  = (float*)ws;                                   // 8,388,608 B
    unsigned short* hbuf  = (unsigned short*)(ws + 8388608);              // 4,194,304 B
    unsigned short* wslot = (unsigned short*)(ws + 12582912);             // 33,554,432 B
    char*           arena = ws + 46137344;                                // 50,331,648 B
    unsigned short* qkvb  = (unsigned short*)arena;                       // 12,582,912 B
    unsigned short* qb_   = (unsigned short*)(arena + 12582912);          // 4,194,304 B
    unsigned short* kb_   = (unsigned short*)(arena + 16777216);
    unsigned short* vtb   = (unsigned short*)(arena + 20971520);
    unsigned short* attnb = (unsigned short*)(arena + 25165824);
    unsigned short* abuf  = (unsigned short*)arena;                       // 33,554,432 B (attn bufs dead)
    unsigned short* gbuf  = (unsigned short*)(arena + 33554432);          // 16,777,216 B

    unsigned short* qkvw_bf = wslot;
    unsigned short* outw_bf = wslot + 3145728;
    unsigned short* w1_bf   = wslot + 4194304;
    unsigned short* w2_bf   = wslot + 12582912;

    hipMemcpyAsync(xbuf, x, (size_t)2048 * 1024 * 4, hipMemcpyDeviceToDevice, stream);

    for (int i = 0; i < 6; i++) {
        conv_w<<<16384, 256, 0, stream>>>(qkv_w + (size_t)i * 3145728, out_w + (size_t)i * 1048576,
                                          w1 + (size_t)i * 8388608, w2 + (size_t)i * 4194304, wslot);
        rmsnorm_bf<<<2048, 256, 0, stream>>>(xbuf, n1 + (size_t)i * 1024, hbuf);
        gemm_bf<0><<<dim3(24, 16, 1), 256, 0, stream>>>(hbuf, qkvw_bf, qkvb, 3072, 1024);
        rope_bf<<<2048, 512, 0, stream>>>(qkvb, qb_, kb_, vtb);
        attn_bf<<<dim3(32, 16), 256, 0, stream>>>(qb_, kb_, vtb, attnb);
        gemm_bf<1><<<dim3(8, 16, 2), 256, 0, stream>>>(attnb, outw_bf, xbuf, 1024, 1024);
        rmsnorm_bf<<<2048, 256, 0, stream>>>(xbuf, n2 + (size_t)i * 1024, hbuf);
        gemm_bf<0><<<dim3(64, 16, 1), 256, 0, stream>>>(hbuf, w1_bf, abuf, 8192, 1024);
        silu_bf<<<8192, 256, 0, stream>>>(abuf, gbuf);
        gemm_bf<1><<<dim3(8, 16, 4), 256, 0, stream>>>(gbuf, w2_bf, xbuf, 1024, 4096);
    }

    hipMemcpyAsync(d_out, xbuf, (size_t)2048 * 1024 * 4, hipMemcpyDeviceToDevice, stream);
}